// Round 8
// baseline (253.153 us; speedup 1.0000x reference)
//
#include <hip/hip_runtime.h>

#define D_ 256
#define H_ 8
#define C_ 32
#define CAP_ 128
#define NEG_SLOPE 0.2f
#define EPS_ 1e-5f
#define EPB_ 4096            // edges per hist block (16 per thread)

typedef __attribute__((ext_vector_type(8))) short bf16x8;
typedef __attribute__((ext_vector_type(4))) float f32x4;

__device__ __forceinline__ unsigned pk2(float a, float b) {   // 2x f32 -> packed bf16 (RNE)
  unsigned ua = __float_as_uint(a), ub = __float_as_uint(b);
  ua = (ua + 0x7fffu + ((ua >> 16) & 1u)) >> 16;
  ub = (ub + 0x7fffu + ((ub >> 16) & 1u)) >> 16;
  return ua | (ub << 16);
}
__device__ __forceinline__ unsigned short f2b(float a) {
  unsigned ua = __float_as_uint(a);
  return (unsigned short)((ua + 0x7fffu + ((ua >> 16) & 1u)) >> 16);
}
__device__ __forceinline__ float b2f(unsigned short u) { return __uint_as_float(((unsigned)u) << 16); }

// hist role body: 16 strided edges per thread, filtered to dst in [hlo,hhi)
__device__ __forceinline__ void hist_role(const int* __restrict__ ei, int* __restrict__ cnt,
    int* __restrict__ bucket, int E, int hlo, int hhi, int hb, int tid) {
  int base = hb * EPB_;
  for (int j = 0; j < 16; ++j) {
    int e = base + j * 256 + tid;
    if (e < E) {
      int d = ei[E + e];
      if (d >= hlo && d < hhi) {
        int s = ei[e];
        int r = atomicAdd(&cnt[d], 1);
        if (r < CAP_) bucket[(size_t)d * CAP_ + r] = s;
      }
    }
  }
}

// ============ K0: W-transpose prep (blocks [0,256)) || cnt zero (rest) ============
__global__ __launch_bounds__(256) void k_prep_zero(const float* __restrict__ W,
    unsigned short* __restrict__ Wt, int* __restrict__ cnt, int N) {
  if (blockIdx.x < 256) {
    int i = blockIdx.x * 256 + threadIdx.x;           // 65536 total
    int n = i >> 8, k = i & 255;
    Wt[i] = f2b(W[k * 256 + n]);
  } else {
    int n = (blockIdx.x - 256) * 256 + threadIdx.x;
    if (n < N) cnt[n] = 0;
  }
}

// ==== K1: hist(chunk0) || MFMA GEMM (+att-logit epilogue), Bresenham roles ====
__global__ __launch_bounds__(256) void k_hist_gemm(const float* __restrict__ x,
    const unsigned short* __restrict__ Wt, unsigned short* __restrict__ h,
    const int* __restrict__ ei, int* __restrict__ cnt, int* __restrict__ bucket,
    const float* __restrict__ att_src, const float* __restrict__ att_dst,
    float* __restrict__ asrc, float* __restrict__ adst,
    int E, int N, int hlo, int hhi, int GB, int TOT) {
  const long long bid = blockIdx.x;
  const long long gid = (bid * GB) / TOT;
  const bool isg = ((bid + 1) * GB) / TOT > gid;
  if (!isg) {
    hist_role(ei, cnt, bucket, E, hlo, hhi, (int)(bid - gid), threadIdx.x);
    return;
  }
  // ---- GEMM role: 4 waves, tile 64 rows x 256 cols, BK=32 ----
  __shared__ uint4 As4[64 * 4];
  __shared__ uint4 Bs4[256 * 4];
  const int tid = threadIdx.x;
  const int bm = (int)gid * 64;
  const int w = tid >> 6, l = tid & 63;
  const int lrow = l & 15, lk = l >> 4;
  f32x4 acc[4][4];
  #pragma unroll
  for (int m = 0; m < 4; m++)
    #pragma unroll
    for (int n = 0; n < 4; n++) acc[m][n] = (f32x4){0.f, 0.f, 0.f, 0.f};

  const int ar = tid >> 2, aq = tid & 3;
  const bool arv = (bm + ar) < N;
  const float* axp = x + (size_t)(bm + ar) * 256 + aq * 8;
  const unsigned short* bwp = Wt + (size_t)tid * 256;
  const int bx = (tid >> 1) & 3;

  // att weights for this wave's two heads (h0 = 2w, h1 = 2w+1)
  const int hh0 = 2 * w, hh1 = 2 * w + 1;
  const float as00 = att_src[hh0 * 32 + lrow], as01 = att_src[hh0 * 32 + 16 + lrow];
  const float as10 = att_src[hh1 * 32 + lrow], as11 = att_src[hh1 * 32 + 16 + lrow];
  const float ad00 = att_dst[hh0 * 32 + lrow], ad01 = att_dst[hh0 * 32 + 16 + lrow];
  const float ad10 = att_dst[hh1 * 32 + lrow], ad11 = att_dst[hh1 * 32 + 16 + lrow];

  for (int k0 = 0; k0 < 256; k0 += 32) {
    float4 v0 = make_float4(0.f, 0.f, 0.f, 0.f), v1 = v0;
    if (arv) {
      v0 = *(const float4*)(axp + k0);
      v1 = *(const float4*)(axp + k0 + 4);
    }
    uint4 ap;
    ap.x = pk2(v0.x, v0.y); ap.y = pk2(v0.z, v0.w);
    ap.z = pk2(v1.x, v1.y); ap.w = pk2(v1.z, v1.w);
    uint4 b0 = *(const uint4*)(bwp + k0);
    uint4 b1 = *(const uint4*)(bwp + k0 + 8);
    uint4 b2 = *(const uint4*)(bwp + k0 + 16);
    uint4 b3 = *(const uint4*)(bwp + k0 + 24);
    __syncthreads();
    As4[ar * 4 + (aq ^ ((ar >> 1) & 3))] = ap;
    Bs4[tid * 4 + (0 ^ bx)] = b0;
    Bs4[tid * 4 + (1 ^ bx)] = b1;
    Bs4[tid * 4 + (2 ^ bx)] = b2;
    Bs4[tid * 4 + (3 ^ bx)] = b3;
    __syncthreads();
    bf16x8 a[4], b[4];
    #pragma unroll
    for (int m = 0; m < 4; m++) {
      int r = m * 16 + lrow;
      a[m] = *(const bf16x8*)&As4[r * 4 + (lk ^ ((r >> 1) & 3))];
    }
    #pragma unroll
    for (int n = 0; n < 4; n++) {
      int rb = w * 64 + n * 16 + lrow;
      b[n] = *(const bf16x8*)&Bs4[rb * 4 + (lk ^ ((rb >> 1) & 3))];
    }
    #pragma unroll
    for (int m = 0; m < 4; m++)
      #pragma unroll
      for (int n = 0; n < 4; n++)
        acc[m][n] = __builtin_amdgcn_mfma_f32_16x16x32_bf16(a[m], b[n], acc[m][n], 0, 0, 0);
  }
  // epilogue: store bf16 h + compute att logits from f32 acc
  #pragma unroll
  for (int m = 0; m < 4; m++) {
    #pragma unroll
    for (int reg = 0; reg < 4; reg++) {
      int row = bm + m * 16 + lk * 4 + reg;
      float v0 = acc[m][0][reg], v1 = acc[m][1][reg];
      float v2 = acc[m][2][reg], v3 = acc[m][3][reg];
      if (row < N) {
        h[(size_t)row * 256 + w * 64 + 0 * 16 + lrow] = f2b(v0);
        h[(size_t)row * 256 + w * 64 + 1 * 16 + lrow] = f2b(v1);
        h[(size_t)row * 256 + w * 64 + 2 * 16 + lrow] = f2b(v2);
        h[(size_t)row * 256 + w * 64 + 3 * 16 + lrow] = f2b(v3);
      }
      float ps0 = v0 * as00 + v1 * as01;
      float ps1 = v2 * as10 + v3 * as11;
      float pd0 = v0 * ad00 + v1 * ad01;
      float pd1 = v2 * ad10 + v3 * ad11;
      #pragma unroll
      for (int off = 1; off < 16; off <<= 1) {
        ps0 += __shfl_xor(ps0, off);
        ps1 += __shfl_xor(ps1, off);
        pd0 += __shfl_xor(pd0, off);
        pd1 += __shfl_xor(pd1, off);
      }
      if (lrow == 0 && row < N) {
        asrc[row * 8 + hh0] = ps0;
        asrc[row * 8 + hh1] = ps1;
        adst[row * 8 + hh0] = pd0;
        adst[row * 8 + hh1] = pd1;
      }
    }
  }
}

// ==== K2..K5: flash gather (nodes [glo,ghi)) || hist (dst [hlo,hhi)), Bresenham ====
__global__ __launch_bounds__(256) void k_gather_hist(const int* __restrict__ cnt,
    const int* __restrict__ bucket, const float* __restrict__ asrc,
    const float* __restrict__ adst, const unsigned short* __restrict__ h,
    const float* __restrict__ x, const float* __restrict__ bias,
    const float* __restrict__ lnw, const float* __restrict__ lnb,
    float* __restrict__ out, const int* __restrict__ ei,
    int* __restrict__ cntw, int* __restrict__ bucketw,
    int E, int N, int glo, int ghi, int hlo, int hhi, int GB, int TOT) {
  const long long bid = blockIdx.x;
  const long long gid = (bid * GB) / TOT;
  const bool isg = ((bid + 1) * GB) / TOT > gid;
  const int tid = threadIdx.x;
  if (!isg) {
    hist_role(ei, cntw, bucketw, E, hlo, hhi, (int)(bid - gid), tid);
    return;
  }
  int wid = glo + ((int)gid * 4) + (tid >> 6);
  if (wid >= ghi) return;
  const int lane = tid & 63;
  const int hd = lane >> 3;
  const char* __restrict__ hB = (const char*)h;      // row stride 512 B -> s<<9
  const char* __restrict__ aB = (const char*)asrc;   // row stride 32 B  -> s<<5
  const unsigned hoff = (unsigned)lane * 8u;
  const unsigned aoff = (unsigned)hd * 4u;
  const float ad = adst[((unsigned)wid << 3) + hd];

  // seed online softmax with the self-loop: m = a_self, p_self = 1, acc = h[wid]
  float a_self = *(const float*)(aB + (((unsigned)wid) << 5) + aoff) + ad;
  a_self = a_self > 0.f ? a_self : NEG_SLOPE * a_self;
  float m = a_self, ssum = 1.f;
  ushort4 hs = *(const ushort4*)(hB + (((unsigned)wid) << 9) + hoff);
  float acc0 = b2f(hs.x), acc1 = b2f(hs.y), acc2 = b2f(hs.z), acc3 = b2f(hs.w);

  const int len = min(cnt[wid], CAP_);
  const int* __restrict__ bp = bucket + (size_t)wid * CAP_;
  int i = 0;
  for (; i + 8 <= len; i += 8) {
    int4 sA = *(const int4*)(bp + i);
    int4 sB = *(const int4*)(bp + i + 4);
    float a0 = *(const float*)(aB + (((unsigned)sA.x) << 5) + aoff) + ad;
    float a1 = *(const float*)(aB + (((unsigned)sA.y) << 5) + aoff) + ad;
    float a2 = *(const float*)(aB + (((unsigned)sA.z) << 5) + aoff) + ad;
    float a3 = *(const float*)(aB + (((unsigned)sA.w) << 5) + aoff) + ad;
    float a4 = *(const float*)(aB + (((unsigned)sB.x) << 5) + aoff) + ad;
    float a5 = *(const float*)(aB + (((unsigned)sB.y) << 5) + aoff) + ad;
    float a6 = *(const float*)(aB + (((unsigned)sB.z) << 5) + aoff) + ad;
    float a7 = *(const float*)(aB + (((unsigned)sB.w) << 5) + aoff) + ad;
    ushort4 q0 = *(const ushort4*)(hB + (((unsigned)sA.x) << 9) + hoff);
    ushort4 q1 = *(const ushort4*)(hB + (((unsigned)sA.y) << 9) + hoff);
    ushort4 q2 = *(const ushort4*)(hB + (((unsigned)sA.z) << 9) + hoff);
    ushort4 q3 = *(const ushort4*)(hB + (((unsigned)sA.w) << 9) + hoff);
    ushort4 q4 = *(const ushort4*)(hB + (((unsigned)sB.x) << 9) + hoff);
    ushort4 q5 = *(const ushort4*)(hB + (((unsigned)sB.y) << 9) + hoff);
    ushort4 q6 = *(const ushort4*)(hB + (((unsigned)sB.z) << 9) + hoff);
    ushort4 q7 = *(const ushort4*)(hB + (((unsigned)sB.w) << 9) + hoff);
    a0 = a0 > 0.f ? a0 : NEG_SLOPE * a0;
    a1 = a1 > 0.f ? a1 : NEG_SLOPE * a1;
    a2 = a2 > 0.f ? a2 : NEG_SLOPE * a2;
    a3 = a3 > 0.f ? a3 : NEG_SLOPE * a3;
    a4 = a4 > 0.f ? a4 : NEG_SLOPE * a4;
    a5 = a5 > 0.f ? a5 : NEG_SLOPE * a5;
    a6 = a6 > 0.f ? a6 : NEG_SLOPE * a6;
    a7 = a7 > 0.f ? a7 : NEG_SLOPE * a7;
    float mx = fmaxf(fmaxf(fmaxf(a0, a1), fmaxf(a2, a3)),
                     fmaxf(fmaxf(a4, a5), fmaxf(a6, a7)));
    if (mx - m > 8.f) {                      // defer-max rescale (rare)
      float r = __expf(m - mx);
      acc0 *= r; acc1 *= r; acc2 *= r; acc3 *= r; ssum *= r; m = mx;
    }
    float p0 = __expf(a0 - m), p1 = __expf(a1 - m);
    float p2 = __expf(a2 - m), p3 = __expf(a3 - m);
    float p4 = __expf(a4 - m), p5 = __expf(a5 - m);
    float p6 = __expf(a6 - m), p7 = __expf(a7 - m);
    ssum += ((p0 + p1) + (p2 + p3)) + ((p4 + p5) + (p6 + p7));
    acc0 = fmaf(p0, b2f(q0.x), fmaf(p1, b2f(q1.x), fmaf(p2, b2f(q2.x), fmaf(p3, b2f(q3.x),
           fmaf(p4, b2f(q4.x), fmaf(p5, b2f(q5.x), fmaf(p6, b2f(q6.x), fmaf(p7, b2f(q7.x), acc0))))))));
    acc1 = fmaf(p0, b2f(q0.y), fmaf(p1, b2f(q1.y), fmaf(p2, b2f(q2.y), fmaf(p3, b2f(q3.y),
           fmaf(p4, b2f(q4.y), fmaf(p5, b2f(q5.y), fmaf(p6, b2f(q6.y), fmaf(p7, b2f(q7.y), acc1))))))));
    acc2 = fmaf(p0, b2f(q0.z), fmaf(p1, b2f(q1.z), fmaf(p2, b2f(q2.z), fmaf(p3, b2f(q3.z),
           fmaf(p4, b2f(q4.z), fmaf(p5, b2f(q5.z), fmaf(p6, b2f(q6.z), fmaf(p7, b2f(q7.z), acc2))))))));
    acc3 = fmaf(p0, b2f(q0.w), fmaf(p1, b2f(q1.w), fmaf(p2, b2f(q2.w), fmaf(p3, b2f(q3.w),
           fmaf(p4, b2f(q4.w), fmaf(p5, b2f(q5.w), fmaf(p6, b2f(q6.w), fmaf(p7, b2f(q7.w), acc3))))))));
  }
  for (; i < len; ++i) {
    int s0 = bp[i];
    float a0 = *(const float*)(aB + (((unsigned)s0) << 5) + aoff) + ad;
    ushort4 q0 = *(const ushort4*)(hB + (((unsigned)s0) << 9) + hoff);
    a0 = a0 > 0.f ? a0 : NEG_SLOPE * a0;
    if (a0 - m > 8.f) {
      float r = __expf(m - a0);
      acc0 *= r; acc1 *= r; acc2 *= r; acc3 *= r; ssum *= r; m = a0;
    }
    float p0 = __expf(a0 - m);
    ssum += p0;
    acc0 = fmaf(p0, b2f(q0.x), acc0);
    acc1 = fmaf(p0, b2f(q0.y), acc1);
    acc2 = fmaf(p0, b2f(q0.z), acc2);
    acc3 = fmaf(p0, b2f(q0.w), acc3);
  }
  const float inv = 1.f / ssum;

  const int c0 = lane * 4;
  float4 xb = *(const float4*)(x + (size_t)wid * D_ + c0);
  float4 bb = *(const float4*)(bias + c0);
  float y0 = acc0 * inv + bb.x + xb.x;
  float y1 = acc1 * inv + bb.y + xb.y;
  float y2 = acc2 * inv + bb.z + xb.z;
  float y3 = acc3 * inv + bb.w + xb.w;
  float sv = y0 + y1 + y2 + y3;
  float qv = y0 * y0 + y1 * y1 + y2 * y2 + y3 * y3;
  #pragma unroll
  for (int off = 1; off < 64; off <<= 1) {
    sv += __shfl_xor(sv, off);
    qv += __shfl_xor(qv, off);
  }
  float mu = sv * (1.f / 256.f);
  float var = qv * (1.f / 256.f) - mu * mu;
  float rs = rsqrtf(var + EPS_);
  float4 lw = *(const float4*)(lnw + c0);
  float4 lb = *(const float4*)(lnb + c0);
  float4 o;
  o.x = (y0 - mu) * rs * lw.x + lb.x;
  o.y = (y1 - mu) * rs * lw.y + lb.y;
  o.z = (y2 - mu) * rs * lw.z + lb.z;
  o.w = (y3 - mu) * rs * lw.w + lb.w;
  *(float4*)(out + (size_t)wid * D_ + c0) = o;
}

extern "C" void kernel_launch(void* const* d_in, const int* in_sizes, int n_in,
                              void* d_out, int out_size, void* d_ws, size_t ws_size,
                              hipStream_t stream) {
  const float* x       = (const float*)d_in[0];
  const int*   ei      = (const int*)d_in[1];
  const float* W       = (const float*)d_in[2];
  const float* att_src = (const float*)d_in[3];
  const float* att_dst = (const float*)d_in[4];
  const float* bias    = (const float*)d_in[5];
  const float* lnw     = (const float*)d_in[6];
  const float* lnb     = (const float*)d_in[7];
  const int N = in_sizes[0] / D_;
  const int E = in_sizes[1] / 2;
  float* out = (float*)d_out;

  char* w = (char*)d_ws;
  unsigned short* Wt = (unsigned short*)w; w += (size_t)256 * 256 * 2;
  unsigned short* h  = (unsigned short*)w; w += (size_t)N * D_ * 2;
  float* asrc   = (float*)w; w += (size_t)N * H_ * 4;
  float* adst   = (float*)w; w += (size_t)N * H_ * 4;
  int*   cnt    = (int*)w;   w += (size_t)N * 4;
  int*   bucket = (int*)w;   w += (size_t)N * CAP_ * 4;

  const int NCH = 4;
  const int NC = (N + NCH - 1) / NCH;
  const int HB = (E + EPB_ - 1) / EPB_;

  // K0: prep Wt || zero cnt
  k_prep_zero<<<256 + (N + 255) / 256, 256, 0, stream>>>(W, Wt, cnt, N);

  // K1: gemm + att-logit epilogue || hist chunk 0
  const int GB = (N + 63) / 64;
  k_hist_gemm<<<GB + HB, 256, 0, stream>>>(x, Wt, h, ei, cnt, bucket,
                                           att_src, att_dst, asrc, adst,
                                           E, N, 0, NC, GB, GB + HB);

  // K2..K5: gather chunk c || hist chunk c+1
  for (int c = 0; c < NCH; ++c) {
    int glo = c * NC, ghi = min(N, glo + NC);
    int hlo = (c + 1) * NC, hhi = min(N, hlo + NC);
    int hb = (c + 1 < NCH) ? HB : 0;
    if (hlo >= hhi) hb = 0;
    int gb = (ghi - glo + 3) / 4;
    k_gather_hist<<<gb + hb, 256, 0, stream>>>(cnt, bucket, asrc, adst, h,
                                               x, bias, lnw, lnb, out, ei,
                                               cnt, bucket, E, N,
                                               glo, ghi, hlo, hhi, gb, gb + hb);
  }
}

// Round 9
// 177.246 us; speedup vs baseline: 1.4283x; 1.4283x over previous
//
#include <hip/hip_runtime.h>

#define D_ 256
#define H_ 8
#define C_ 32
#define CAP_ 128
#define NEG_SLOPE 0.2f
#define EPS_ 1e-5f

typedef __attribute__((ext_vector_type(8))) short bf16x8;
typedef __attribute__((ext_vector_type(4))) float f32x4;
typedef __attribute__((ext_vector_type(2))) float f32x2;

__device__ __forceinline__ unsigned pk2(float a, float b) {   // 2x f32 -> packed bf16 (RNE)
  unsigned ua = __float_as_uint(a), ub = __float_as_uint(b);
  ua = (ua + 0x7fffu + ((ua >> 16) & 1u)) >> 16;
  ub = (ub + 0x7fffu + ((ub >> 16) & 1u)) >> 16;
  return ua | (ub << 16);
}
__device__ __forceinline__ unsigned short f2b(float a) {
  unsigned ua = __float_as_uint(a);
  return (unsigned short)((ua + 0x7fffu + ((ua >> 16) & 1u)) >> 16);
}

// ---------------- fp8 e4m3fn encode/decode (HW cvt if available) ----------------
#if defined(__has_builtin)
#if __has_builtin(__builtin_amdgcn_cvt_pk_fp8_f32) && __has_builtin(__builtin_amdgcn_cvt_pk_f32_fp8)
#define HW_FP8 1
#endif
#endif

__device__ __forceinline__ unsigned enc2_fp8(float a, float b) {  // byte0=fp8(a), byte1=fp8(b)
#ifdef HW_FP8
  return ((unsigned)__builtin_amdgcn_cvt_pk_fp8_f32(a, b, 0, false)) & 0xffffu;
#else
  unsigned r = 0;
  float vv[2] = {a, b};
  #pragma unroll
  for (int i = 0; i < 2; i++) {
    float v = vv[i];
    unsigned u = __float_as_uint(v);
    unsigned s = (u >> 31) << 7;
    float av = fabsf(v);
    unsigned byte;
    if (av < 0.015625f) byte = s;                    // flush subnormal
    else if (av >= 448.f) byte = s | 0x7e;           // clamp to max finite
    else {
      unsigned ua = u & 0x7fffffffu;
      ua += 0x0007ffffu + ((ua >> 20) & 1u);         // RNE to 3-bit mantissa
      unsigned e = (ua >> 23) - 120u;                // e-127+7
      unsigned m = (ua >> 20) & 7u;
      byte = s | (e << 3) | m;
    }
    r |= byte << (8 * i);
  }
  return r;
#endif
}

__device__ __forceinline__ float dec1_fp8(unsigned b) {
  unsigned s = (b >> 7) & 1u, em = b & 0x7fu;
  float v = (em >= 8u) ? __uint_as_float((((em >> 3) + 120u) << 23) | ((em & 7u) << 20))
                       : (float)em * 0.001953125f;   // 2^-9
  return s ? -v : v;
}

// decode 4 fp8 bytes -> 4 floats
__device__ __forceinline__ void dec4_fp8(unsigned q, float& f0, float& f1, float& f2, float& f3) {
#ifdef HW_FP8
  f32x2 lo = __builtin_amdgcn_cvt_pk_f32_fp8((int)q, false);
  f32x2 hi = __builtin_amdgcn_cvt_pk_f32_fp8((int)q, true);
  f0 = lo[0]; f1 = lo[1]; f2 = hi[0]; f3 = hi[1];
#else
  f0 = dec1_fp8(q & 0xffu); f1 = dec1_fp8((q >> 8) & 0xffu);
  f2 = dec1_fp8((q >> 16) & 0xffu); f3 = dec1_fp8(q >> 24);
#endif
}

// ============ K0: W-transpose prep (blocks [0,256)) || cnt zero (rest) ============
__global__ __launch_bounds__(256) void k_prep_zero(const float* __restrict__ W,
    unsigned short* __restrict__ Wt, int* __restrict__ cnt, int N) {
  if (blockIdx.x < 256) {
    int i = blockIdx.x * 256 + threadIdx.x;           // 65536 total
    int n = i >> 8, k = i & 255;
    Wt[i] = f2b(W[k * 256 + n]);
  } else {
    int n = (blockIdx.x - 256) * 256 + threadIdx.x;
    if (n < N) cnt[n] = 0;
  }
}

// ==== K1: hist + bucket-scatter || MFMA GEMM (+att-logit epilogue, fp8 h store) ====
__global__ __launch_bounds__(256) void k_hist_gemm(const float* __restrict__ x,
    const unsigned short* __restrict__ Wt, unsigned char* __restrict__ h,
    const int* __restrict__ ei, int* __restrict__ cnt, int* __restrict__ bucket,
    const float* __restrict__ att_src, const float* __restrict__ att_dst,
    float* __restrict__ asrc, float* __restrict__ adst,
    int E, int N, int GB, int TOT) {
  const long long bid = blockIdx.x;
  const long long gid = (bid * GB) / TOT;
  const bool isg = ((bid + 1) * GB) / TOT > gid;
  if (!isg) {
    // ---- hist role: 1 edge/thread (max TLP for atomic pipelining) ----
    int hb = (int)(bid - gid);
    int e = hb * 256 + threadIdx.x;
    if (e < E) {
      int s = ei[e], d = ei[E + e];
      int r = atomicAdd(&cnt[d], 1);
      if (r < CAP_) bucket[(size_t)d * CAP_ + r] = s;   // CAP_ >> max degree
    }
    return;
  }
  // ---- GEMM role: 4 waves, tile 64 rows x 256 cols, BK=32 ----
  __shared__ uint4 As4[64 * 4];
  __shared__ uint4 Bs4[256 * 4];
  const int tid = threadIdx.x;
  const int bm = (int)gid * 64;
  const int w = tid >> 6, l = tid & 63;
  const int lrow = l & 15, lk = l >> 4;
  f32x4 acc[4][4];
  #pragma unroll
  for (int m = 0; m < 4; m++)
    #pragma unroll
    for (int n = 0; n < 4; n++) acc[m][n] = (f32x4){0.f, 0.f, 0.f, 0.f};

  const int ar = tid >> 2, aq = tid & 3;
  const bool arv = (bm + ar) < N;
  const float* axp = x + (size_t)(bm + ar) * 256 + aq * 8;
  const unsigned short* bwp = Wt + (size_t)tid * 256;
  const int bx = (tid >> 1) & 3;

  // att weights for this wave's two heads (h0 = 2w, h1 = 2w+1)
  const int hh0 = 2 * w, hh1 = 2 * w + 1;
  const float as00 = att_src[hh0 * 32 + lrow], as01 = att_src[hh0 * 32 + 16 + lrow];
  const float as10 = att_src[hh1 * 32 + lrow], as11 = att_src[hh1 * 32 + 16 + lrow];
  const float ad00 = att_dst[hh0 * 32 + lrow], ad01 = att_dst[hh0 * 32 + 16 + lrow];
  const float ad10 = att_dst[hh1 * 32 + lrow], ad11 = att_dst[hh1 * 32 + 16 + lrow];

  for (int k0 = 0; k0 < 256; k0 += 32) {
    float4 v0 = make_float4(0.f, 0.f, 0.f, 0.f), v1 = v0;
    if (arv) {
      v0 = *(const float4*)(axp + k0);
      v1 = *(const float4*)(axp + k0 + 4);
    }
    uint4 ap;
    ap.x = pk2(v0.x, v0.y); ap.y = pk2(v0.z, v0.w);
    ap.z = pk2(v1.x, v1.y); ap.w = pk2(v1.z, v1.w);
    uint4 b0 = *(const uint4*)(bwp + k0);
    uint4 b1 = *(const uint4*)(bwp + k0 + 8);
    uint4 b2 = *(const uint4*)(bwp + k0 + 16);
    uint4 b3 = *(const uint4*)(bwp + k0 + 24);
    __syncthreads();
    As4[ar * 4 + (aq ^ ((ar >> 1) & 3))] = ap;
    Bs4[tid * 4 + (0 ^ bx)] = b0;
    Bs4[tid * 4 + (1 ^ bx)] = b1;
    Bs4[tid * 4 + (2 ^ bx)] = b2;
    Bs4[tid * 4 + (3 ^ bx)] = b3;
    __syncthreads();
    bf16x8 a[4], b[4];
    #pragma unroll
    for (int m = 0; m < 4; m++) {
      int r = m * 16 + lrow;
      a[m] = *(const bf16x8*)&As4[r * 4 + (lk ^ ((r >> 1) & 3))];
    }
    #pragma unroll
    for (int n = 0; n < 4; n++) {
      int rb = w * 64 + n * 16 + lrow;
      b[n] = *(const bf16x8*)&Bs4[rb * 4 + (lk ^ ((rb >> 1) & 3))];
    }
    #pragma unroll
    for (int m = 0; m < 4; m++)
      #pragma unroll
      for (int n = 0; n < 4; n++)
        acc[m][n] = __builtin_amdgcn_mfma_f32_16x16x32_bf16(a[m], b[n], acc[m][n], 0, 0, 0);
  }
  // epilogue: store fp8 h + compute att logits from f32 acc
  #pragma unroll
  for (int m = 0; m < 4; m++) {
    #pragma unroll
    for (int reg = 0; reg < 4; reg++) {
      int row = bm + m * 16 + lk * 4 + reg;
      float v0 = acc[m][0][reg], v1 = acc[m][1][reg];
      float v2 = acc[m][2][reg], v3 = acc[m][3][reg];
      if (row < N) {
        unsigned pa = enc2_fp8(v0, v1);
        unsigned pb = enc2_fp8(v2, v3);
        unsigned char* hp = h + (size_t)row * 256 + w * 64 + lrow;
        hp[0]  = (unsigned char)(pa & 0xff);
        hp[16] = (unsigned char)((pa >> 8) & 0xff);
        hp[32] = (unsigned char)(pb & 0xff);
        hp[48] = (unsigned char)((pb >> 8) & 0xff);
      }
      float ps0 = v0 * as00 + v1 * as01;
      float ps1 = v2 * as10 + v3 * as11;
      float pd0 = v0 * ad00 + v1 * ad01;
      float pd1 = v2 * ad10 + v3 * ad11;
      #pragma unroll
      for (int off = 1; off < 16; off <<= 1) {
        ps0 += __shfl_xor(ps0, off);
        ps1 += __shfl_xor(ps1, off);
        pd0 += __shfl_xor(pd0, off);
        pd1 += __shfl_xor(pd1, off);
      }
      if (lrow == 0 && row < N) {
        asrc[row * 8 + hh0] = ps0;
        asrc[row * 8 + hh1] = ps1;
        adst[row * 8 + hh0] = pd0;
        adst[row * 8 + hh1] = pd1;
      }
    }
  }
}

// ============ K2: flash gather (fp8 h) + self-loop + bias + residual + LN ============
// one wave per dst node; lane owns channels 4*lane..4*lane+3, head hd = lane>>3
__global__ __launch_bounds__(256) void k_gather(const int* __restrict__ cnt,
    const int* __restrict__ bucket, const float* __restrict__ asrc,
    const float* __restrict__ adst, const unsigned char* __restrict__ h,
    const float* __restrict__ x, const float* __restrict__ bias,
    const float* __restrict__ lnw, const float* __restrict__ lnb,
    float* __restrict__ out, int N) {
  int wid = (blockIdx.x * 256 + threadIdx.x) >> 6;
  if (wid >= N) return;
  const int lane = threadIdx.x & 63;
  const int hd = lane >> 3;
  const char* __restrict__ hB = (const char*)h;      // row stride 256 B -> s<<8
  const char* __restrict__ aB = (const char*)asrc;   // row stride 32 B  -> s<<5
  const unsigned hoff = (unsigned)lane * 4u;
  const unsigned aoff = (unsigned)hd * 4u;
  const float ad = adst[((unsigned)wid << 3) + hd];

  // seed online softmax with the self-loop: m = a_self, p_self = 1, acc = h[wid]
  float a_self = *(const float*)(aB + (((unsigned)wid) << 5) + aoff) + ad;
  a_self = a_self > 0.f ? a_self : NEG_SLOPE * a_self;
  float m = a_self, ssum = 1.f;
  float acc0, acc1, acc2, acc3;
  {
    unsigned qs = *(const unsigned*)(hB + (((unsigned)wid) << 8) + hoff);
    dec4_fp8(qs, acc0, acc1, acc2, acc3);
  }

  const int len = min(cnt[wid], CAP_);
  const int* __restrict__ bp = bucket + (size_t)wid * CAP_;
  int i = 0;
  for (; i + 8 <= len; i += 8) {
    int4 sA = *(const int4*)(bp + i);
    int4 sB = *(const int4*)(bp + i + 4);
    float a0 = *(const float*)(aB + (((unsigned)sA.x) << 5) + aoff) + ad;
    float a1 = *(const float*)(aB + (((unsigned)sA.y) << 5) + aoff) + ad;
    float a2 = *(const float*)(aB + (((unsigned)sA.z) << 5) + aoff) + ad;
    float a3 = *(const float*)(aB + (((unsigned)sA.w) << 5) + aoff) + ad;
    float a4 = *(const float*)(aB + (((unsigned)sB.x) << 5) + aoff) + ad;
    float a5 = *(const float*)(aB + (((unsigned)sB.y) << 5) + aoff) + ad;
    float a6 = *(const float*)(aB + (((unsigned)sB.z) << 5) + aoff) + ad;
    float a7 = *(const float*)(aB + (((unsigned)sB.w) << 5) + aoff) + ad;
    unsigned q0 = *(const unsigned*)(hB + (((unsigned)sA.x) << 8) + hoff);
    unsigned q1 = *(const unsigned*)(hB + (((unsigned)sA.y) << 8) + hoff);
    unsigned q2 = *(const unsigned*)(hB + (((unsigned)sA.z) << 8) + hoff);
    unsigned q3 = *(const unsigned*)(hB + (((unsigned)sA.w) << 8) + hoff);
    unsigned q4 = *(const unsigned*)(hB + (((unsigned)sB.x) << 8) + hoff);
    unsigned q5 = *(const unsigned*)(hB + (((unsigned)sB.y) << 8) + hoff);
    unsigned q6 = *(const unsigned*)(hB + (((unsigned)sB.z) << 8) + hoff);
    unsigned q7 = *(const unsigned*)(hB + (((unsigned)sB.w) << 8) + hoff);
    a0 = a0 > 0.f ? a0 : NEG_SLOPE * a0;
    a1 = a1 > 0.f ? a1 : NEG_SLOPE * a1;
    a2 = a2 > 0.f ? a2 : NEG_SLOPE * a2;
    a3 = a3 > 0.f ? a3 : NEG_SLOPE * a3;
    a4 = a4 > 0.f ? a4 : NEG_SLOPE * a4;
    a5 = a5 > 0.f ? a5 : NEG_SLOPE * a5;
    a6 = a6 > 0.f ? a6 : NEG_SLOPE * a6;
    a7 = a7 > 0.f ? a7 : NEG_SLOPE * a7;
    float mx = fmaxf(fmaxf(fmaxf(a0, a1), fmaxf(a2, a3)),
                     fmaxf(fmaxf(a4, a5), fmaxf(a6, a7)));
    if (mx - m > 8.f) {                      // defer-max rescale (rare)
      float r = __expf(m - mx);
      acc0 *= r; acc1 *= r; acc2 *= r; acc3 *= r; ssum *= r; m = mx;
    }
    float p0 = __expf(a0 - m), p1 = __expf(a1 - m);
    float p2 = __expf(a2 - m), p3 = __expf(a3 - m);
    float p4 = __expf(a4 - m), p5 = __expf(a5 - m);
    float p6 = __expf(a6 - m), p7 = __expf(a7 - m);
    ssum += ((p0 + p1) + (p2 + p3)) + ((p4 + p5) + (p6 + p7));
    float f0, f1, f2, f3;
    dec4_fp8(q0, f0, f1, f2, f3);
    acc0 = fmaf(p0, f0, acc0); acc1 = fmaf(p0, f1, acc1);
    acc2 = fmaf(p0, f2, acc2); acc3 = fmaf(p0, f3, acc3);
    dec4_fp8(q1, f0, f1, f2, f3);
    acc0 = fmaf(p1, f0, acc0); acc1 = fmaf(p1, f1, acc1);
    acc2 = fmaf(p1, f2, acc2); acc3 = fmaf(p1, f3, acc3);
    dec4_fp8(q2, f0, f1, f2, f3);
    acc0 = fmaf(p2, f0, acc0); acc1 = fmaf(p2, f1, acc1);
    acc2 = fmaf(p2, f2, acc2); acc3 = fmaf(p2, f3, acc3);
    dec4_fp8(q3, f0, f1, f2, f3);
    acc0 = fmaf(p3, f0, acc0); acc1 = fmaf(p3, f1, acc1);
    acc2 = fmaf(p3, f2, acc2); acc3 = fmaf(p3, f3, acc3);
    dec4_fp8(q4, f0, f1, f2, f3);
    acc0 = fmaf(p4, f0, acc0); acc1 = fmaf(p4, f1, acc1);
    acc2 = fmaf(p4, f2, acc2); acc3 = fmaf(p4, f3, acc3);
    dec4_fp8(q5, f0, f1, f2, f3);
    acc0 = fmaf(p5, f0, acc0); acc1 = fmaf(p5, f1, acc1);
    acc2 = fmaf(p5, f2, acc2); acc3 = fmaf(p5, f3, acc3);
    dec4_fp8(q6, f0, f1, f2, f3);
    acc0 = fmaf(p6, f0, acc0); acc1 = fmaf(p6, f1, acc1);
    acc2 = fmaf(p6, f2, acc2); acc3 = fmaf(p6, f3, acc3);
    dec4_fp8(q7, f0, f1, f2, f3);
    acc0 = fmaf(p7, f0, acc0); acc1 = fmaf(p7, f1, acc1);
    acc2 = fmaf(p7, f2, acc2); acc3 = fmaf(p7, f3, acc3);
  }
  for (; i < len; ++i) {
    int s0 = bp[i];
    float a0 = *(const float*)(aB + (((unsigned)s0) << 5) + aoff) + ad;
    unsigned q0 = *(const unsigned*)(hB + (((unsigned)s0) << 8) + hoff);
    a0 = a0 > 0.f ? a0 : NEG_SLOPE * a0;
    if (a0 - m > 8.f) {
      float r = __expf(m - a0);
      acc0 *= r; acc1 *= r; acc2 *= r; acc3 *= r; ssum *= r; m = a0;
    }
    float p0 = __expf(a0 - m);
    ssum += p0;
    float f0, f1, f2, f3;
    dec4_fp8(q0, f0, f1, f2, f3);
    acc0 = fmaf(p0, f0, acc0); acc1 = fmaf(p0, f1, acc1);
    acc2 = fmaf(p0, f2, acc2); acc3 = fmaf(p0, f3, acc3);
  }
  const float inv = 1.f / ssum;

  const int c0 = lane * 4;
  float4 xb = *(const float4*)(x + (size_t)wid * D_ + c0);
  float4 bb = *(const float4*)(bias + c0);
  float y0 = acc0 * inv + bb.x + xb.x;
  float y1 = acc1 * inv + bb.y + xb.y;
  float y2 = acc2 * inv + bb.z + xb.z;
  float y3 = acc3 * inv + bb.w + xb.w;
  float sv = y0 + y1 + y2 + y3;
  float qv = y0 * y0 + y1 * y1 + y2 * y2 + y3 * y3;
  #pragma unroll
  for (int off = 1; off < 64; off <<= 1) {
    sv += __shfl_xor(sv, off);
    qv += __shfl_xor(qv, off);
  }
  float mu = sv * (1.f / 256.f);
  float var = qv * (1.f / 256.f) - mu * mu;
  float rs = rsqrtf(var + EPS_);
  float4 lw = *(const float4*)(lnw + c0);
  float4 lb = *(const float4*)(lnb + c0);
  float4 o;
  o.x = (y0 - mu) * rs * lw.x + lb.x;
  o.y = (y1 - mu) * rs * lw.y + lb.y;
  o.z = (y2 - mu) * rs * lw.z + lb.z;
  o.w = (y3 - mu) * rs * lw.w + lb.w;
  *(float4*)(out + (size_t)wid * D_ + c0) = o;
}

extern "C" void kernel_launch(void* const* d_in, const int* in_sizes, int n_in,
                              void* d_out, int out_size, void* d_ws, size_t ws_size,
                              hipStream_t stream) {
  const float* x       = (const float*)d_in[0];
  const int*   ei      = (const int*)d_in[1];
  const float* W       = (const float*)d_in[2];
  const float* att_src = (const float*)d_in[3];
  const float* att_dst = (const float*)d_in[4];
  const float* bias    = (const float*)d_in[5];
  const float* lnw     = (const float*)d_in[6];
  const float* lnb     = (const float*)d_in[7];
  const int N = in_sizes[0] / D_;
  const int E = in_sizes[1] / 2;
  float* out = (float*)d_out;

  char* w = (char*)d_ws;
  unsigned short* Wt = (unsigned short*)w; w += (size_t)256 * 256 * 2;
  unsigned char*  h  = (unsigned char*)w;  w += (size_t)N * D_;
  w += ((size_t)16 - ((size_t)w & 15)) & 15;   // realign to 16B
  float* asrc   = (float*)w; w += (size_t)N * H_ * 4;
  float* adst   = (float*)w; w += (size_t)N * H_ * 4;
  int*   cnt    = (int*)w;   w += (size_t)N * 4;
  int*   bucket = (int*)w;   w += (size_t)N * CAP_ * 4;

  // K0: prep Wt || zero cnt
  k_prep_zero<<<256 + (N + 255) / 256, 256, 0, stream>>>(W, Wt, cnt, N);

  // K1: hist + bucket scatter || gemm + att-logit epilogue (fp8 h)
  const int HB = (E + 255) / 256;
  const int GB = (N + 63) / 64;
  const int TOT = HB + GB;
  k_hist_gemm<<<TOT, 256, 0, stream>>>(x, Wt, h, ei, cnt, bucket,
                                       att_src, att_dst, asrc, adst, E, N, GB, TOT);

  // K2: flash gather + epilogue
  k_gather<<<(N * 64 + 255) / 256, 256, 0, stream>>>(cnt, bucket, asrc, adst, h,
                                                     x, bias, lnw, lnb, out, N);
}